// Round 14
// baseline (677.832 us; speedup 1.0000x reference)
//
#include <hip/hip_runtime.h>
#include <hip/hip_bf16.h>

// DynaLoRALinear via K-augmented bf16 GEMM:
//   x_aug[row][0:4096]=bf16(x), [4096:4128]=gate*t, [4128:4160]=0
//   W_aug[o][0:4096]=bf16(W_base), [4096+e*8+r]=bf16(lora_B[e,o,r]), rest 0
//   out = x_aug @ W_aug^T + b_base   (M=16384, N=4096, K=4160)
// GEMM R13: R8 slot/vmcnt discipline (ring-of-5 K=32 slots, 160 KB LDS,
// 1 barrier + vmcnt(4) per 2-group pair) with the pair body re-ordered into
// alternating {reads for NEXT cluster} / {MFMA cluster} quadruples so each
// 16-MFMA cluster overlaps the following independent read batch (m196 lever).
// Launches: prep_k (cvt_x+cvt_w+cvt_la+gated), lora_t_k (pipelined + inline
// gate), gemm_k.

typedef short short8 __attribute__((ext_vector_type(8)));
typedef float f32x4v __attribute__((ext_vector_type(4)));

#define M_DIM 16384
#define N_DIM 4096
#define K_DIM 4160   // 65 * 64 = 130 * 32
#define D_DIM 4096
#define NGRP 130     // 32-wide K groups

__device__ __forceinline__ unsigned short f2b(float f) {
  unsigned u = __builtin_bit_cast(unsigned, f);
  return (unsigned short)((u + 0x7FFFu + ((u >> 16) & 1u)) >> 16);  // RNE
}
__device__ __forceinline__ void async_copy16(void* lds, const void* g) {
  __builtin_amdgcn_global_load_lds(
      (const __attribute__((address_space(1))) void*)g,
      (__attribute__((address_space(3))) void*)lds, 16, 0, 0);
}
// 64-col (128 B-row) LDS tiles: phys 16B-slot p of row r holds logical
// l = p ^ (r&7); read logical l at p = l ^ (r&7).
__device__ __forceinline__ short8 frag_ld(const short* base, int row, int ks, int hi, int lo) {
  return *(const short8*)(&base[row * 64 + (((ks * 4 + hi) ^ (lo & 7)) * 8)]);
}
__device__ __forceinline__ short8 cvt8(const float* src) {
  float4 a = *(const float4*)(src);
  float4 b = *(const float4*)(src + 4);
  short8 o;
  o[0] = (short)f2b(a.x); o[1] = (short)f2b(a.y);
  o[2] = (short)f2b(a.z); o[3] = (short)f2b(a.w);
  o[4] = (short)f2b(b.x); o[5] = (short)f2b(b.y);
  o[6] = (short)f2b(b.z); o[7] = (short)f2b(b.w);
  return o;
}

// ---- K1 (fused prep): blocks [0,33280)        cvt_x  -> xa
//                       blocks [33280,41600)    cvt_w  -> wa (+lora_B pack)
//                       blocks [41600,41664)    cvt_la -> lAb
//                       blocks [41664,45760)    gated[b][j] = x_pooled . gW[j]
__global__ __launch_bounds__(256) void prep_k(const float* __restrict__ x,
                                              const float* __restrict__ Wb,
                                              const float* __restrict__ lB,
                                              const float* __restrict__ lA,
                                              const float* __restrict__ gW,
                                              short* __restrict__ xa,
                                              short* __restrict__ wa,
                                              short* __restrict__ lAb,
                                              float* __restrict__ gated) {
  __shared__ float red[8][4];
  const unsigned bid = blockIdx.x;
  const int tid = threadIdx.x;
  if (bid < 33280u) {
    size_t idx = (size_t)bid * 256 + tid;   // 16384*520
    size_t row = idx / 520;
    int cc = (int)(idx % 520);
    short8 o;
    if (cc < 512) {
      o = cvt8(x + row * (size_t)D_DIM + (size_t)cc * 8);
    } else {
#pragma unroll
      for (int t = 0; t < 8; ++t) o[t] = 0;
    }
    *(short8*)(xa + row * (size_t)K_DIM + (size_t)cc * 8) = o;
  } else if (bid < 41600u) {
    size_t idx = (size_t)(bid - 33280u) * 256 + tid;   // 4096*520
    size_t row = idx / 520;
    int cc = (int)(idx % 520);
    short8 o;
    if (cc < 512) {
      o = cvt8(Wb + row * (size_t)D_DIM + (size_t)cc * 8);
    } else if (cc < 516) {
      int e = cc - 512;
      o = cvt8(lB + (size_t)e * (D_DIM * 8) + row * 8);
    } else {
#pragma unroll
      for (int t = 0; t < 8; ++t) o[t] = 0;
    }
    *(short8*)(wa + row * (size_t)K_DIM + (size_t)cc * 8) = o;
  } else if (bid < 41664u) {
    size_t i = (size_t)(bid - 41600u) * 256 + tid;  // 16384 chunks of 8
    *(short8*)(lAb + i * 8) = cvt8(lA + i * 8);
  } else {
    const int j = (int)(bid - 41664u);   // 0..4095
    float acc[8];
#pragma unroll
    for (int b = 0; b < 8; ++b) acc[b] = 0.f;
    const float* w = gW + (size_t)j * D_DIM;
    for (int i = tid * 4; i < D_DIM; i += 1024) {
      float4 wv = *(const float4*)(w + i);
#pragma unroll
      for (int b = 0; b < 8; ++b) {
        const float* p = x + ((size_t)b * 2048 + 2047) * D_DIM + i;
        float4 pv = *(const float4*)p;
        acc[b] += wv.x * pv.x + wv.y * pv.y + wv.z * pv.z + wv.w * pv.w;
      }
    }
    const int lane = tid & 63, wv_ = tid >> 6;
#pragma unroll
    for (int b = 0; b < 8; ++b) {
      float v = acc[b];
      v += __shfl_down(v, 32); v += __shfl_down(v, 16); v += __shfl_down(v, 8);
      v += __shfl_down(v, 4);  v += __shfl_down(v, 2);  v += __shfl_down(v, 1);
      if (lane == 0) red[b][wv_] = v;
    }
    __syncthreads();
    if (tid < 8)
      gated[(size_t)tid * D_DIM + j] = red[tid][0] + red[tid][1] + red[tid][2] + red[tid][3];
  }
}

// ---- K5 (R11 + inline gate): LoRA-A projection, pipelined. 512 blocks x 32
// rows, 4 waves (wave w -> rows (w>>1)*16, cols (w&1)*16). LDS ring-4 of K=64
// slots, stage d=2, vmcnt(2) + 1 barrier/iter. Epilogue recomputes this
// block's batch gate from gated/Wr/scores.
__global__ __launch_bounds__(256) void lora_t_k(const short* __restrict__ XA,
                                                const short* __restrict__ LAb,
                                                const float* __restrict__ gated,
                                                const float* __restrict__ Wr,
                                                const float* __restrict__ scores,
                                                const int* __restrict__ midx_p,
                                                const int* __restrict__ kp,
                                                short* __restrict__ xa_w) {
  __shared__ short As[4][2048];   // 4 slots x (32 rows x 64 K)
  __shared__ short Bs[4][2048];
  __shared__ float Lp[4][7];
  __shared__ float Ls[7];
  __shared__ float gateS[4];
  const int tid = threadIdx.x, lane = tid & 63, wave = tid >> 6;
  const int lo = lane & 15, hi = lane >> 4;
  const int wr = (wave >> 1) * 16;       // row tile 0/16
  const int wc = (wave & 1) * 16;        // col tile 0/16
  const size_t row0 = (size_t)blockIdx.x * 32;
  const int srow = tid >> 3;
  const int sslot = (tid & 7) ^ (srow & 7);
  const short* gA = XA + (row0 + srow) * (size_t)K_DIM + sslot * 8;
  const short* gB = LAb + (size_t)srow * D_DIM + sslot * 8;
  f32x4v acc = {};

#define LSTAGE(g)                                                              \
  async_copy16((char*)&As[(g) & 3][0] + wave * 1024, gA + (size_t)(g) * 64);   \
  async_copy16((char*)&Bs[(g) & 3][0] + wave * 1024, gB + (size_t)(g) * 64);

  LSTAGE(0)
  LSTAGE(1)
  asm volatile("s_waitcnt vmcnt(2)" ::: "memory");   // slot 0 landed
  __builtin_amdgcn_s_barrier();

  for (int g = 0; g < 64; ++g) {
    const short* Atile = &As[g & 3][0];
    const short* Btile = &Bs[g & 3][0];
    short8 a0 = frag_ld(Atile, wr + lo, 0, hi, lo);
    short8 a1 = frag_ld(Atile, wr + lo, 1, hi, lo);
    short8 b0 = frag_ld(Btile, wc + lo, 0, hi, lo);
    short8 b1 = frag_ld(Btile, wc + lo, 1, hi, lo);
    acc = __builtin_amdgcn_mfma_f32_16x16x32_bf16(a0, b0, acc, 0, 0, 0);
    acc = __builtin_amdgcn_mfma_f32_16x16x32_bf16(a1, b1, acc, 0, 0, 0);
    if (g < 62) {
      LSTAGE(g + 2)
      asm volatile("s_waitcnt vmcnt(2)" ::: "memory");  // slot g+1 landed
    } else {
      asm volatile("s_waitcnt vmcnt(0)" ::: "memory");  // tail drain
    }
    __builtin_amdgcn_s_barrier();
  }

  // ---- inline gate for this block's batch
  const int bblk = (int)(row0 >> 11);
  {
    float ac7[7];
#pragma unroll
    for (int m = 0; m < 7; ++m) ac7[m] = 0.f;
    const float* gb = gated + (size_t)bblk * D_DIM;
    for (int i = tid * 4; i < D_DIM; i += 1024) {   // 4 iterations
      float4 g4 = *(const float4*)(gb + i);
#pragma unroll
      for (int m = 0; m < 7; ++m) {
        float4 w4 = *(const float4*)(Wr + (size_t)m * D_DIM + i);
        ac7[m] += w4.x * g4.x + w4.y * g4.y + w4.z * g4.z + w4.w * g4.w;
      }
    }
#pragma unroll
    for (int m = 0; m < 7; ++m) {
      float v = ac7[m];
      v += __shfl_xor(v, 1); v += __shfl_xor(v, 2); v += __shfl_xor(v, 4);
      v += __shfl_xor(v, 8); v += __shfl_xor(v, 16); v += __shfl_xor(v, 32);
      if (lane == m) Lp[wave][m] = v;
    }
    __syncthreads();
    if (tid < 7) Ls[tid] = Lp[0][tid] + Lp[1][tid] + Lp[2][tid] + Lp[3][tid];
    __syncthreads();
    if (tid == 0) {
      float mx = -1e30f;
      for (int m = 0; m < 7; ++m) mx = fmaxf(mx, Ls[m]);
      float s = 0.f;
      for (int m = 0; m < 7; ++m) s += expf(Ls[m] - mx);
      const int mi = midx_p[0];
      const float mp = expf(Ls[mi] - mx) / s;
      int kv = kp[0]; if (kv < 1) kv = 1;
      int klo = kv >> 1; if (klo < 1) klo = 1;
      float sc[4];
#pragma unroll
      for (int e = 0; e < 4; ++e) sc[e] = scores[bblk * 4 + e];
#pragma unroll
      for (int e = 0; e < 4; ++e) {
        int rank = 0;
#pragma unroll
        for (int e2 = 0; e2 < 4; ++e2)
          rank += (sc[e2] > sc[e] || (sc[e2] == sc[e] && e2 < e)) ? 1 : 0;
        gateS[e] = (mp > 0.5f) ? ((rank < kv) ? 1.0f / (float)kv : 0.f)
                               : ((rank < klo) ? 1.0f / (float)klo : 0.f);
      }
    }
    __syncthreads();
  }

  const int col = wc + lo;
  const float gv = gateS[col >> 3];
#pragma unroll
  for (int j = 0; j < 4; ++j) {
    const size_t r = row0 + wr + hi * 4 + j;
    xa_w[r * (size_t)K_DIM + 4096 + col] = (short)f2b(acc[j] * gv);
  }
#undef LSTAGE
}

// ---- K6: main GEMM. R8 sync scheme; pair body alternates {reads for next
// cluster} / {16-MFMA cluster}: M0||R1, M1||R2, M2||R3 independent overlaps.
__global__ __launch_bounds__(512, 2) void gemm_k(const short* __restrict__ A,
                                                 const short* __restrict__ B,
                                                 const float* __restrict__ bias,
                                                 float* __restrict__ C) {
  __shared__ short As[5][8192];   // 5 x 16 KB (256 rows x 32 K)
  __shared__ short Bs[5][8192];
  const int tid = threadIdx.x;
  const int lane = tid & 63;
  const int wave = tid >> 6;            // 0..7
  const int wm = wave >> 2;             // 0..1 -> rows wm*128..+128
  const int wn = wave & 3;              // 0..3 -> cols wn*64..+64
  const int lo = lane & 15, hi = lane >> 4;

  // T1: XCD swizzle (1024 blocks, 8 XCDs, bijective)
  const int wg = (blockIdx.x & 7) * 128 + (blockIdx.x >> 3);
  const int brow = wg >> 4;             // 0..63
  const int bcol = wg & 15;             // 0..15

  // staging: 512 thr x 16 B covers 128 rows x 32 K; row = tid>>2, phys chunk
  // tid&3, logical = phys ^ ((row>>1)&3) = phys ^ ((tid>>3)&3)
  const int srow = tid >> 2;
  const int schunk = (tid & 3) ^ ((tid >> 3) & 3);
  const short* srcA = A + (size_t)(brow * 256 + srow) * K_DIM + schunk * 8;
  const short* srcB = B + (size_t)(bcol * 256 + srow) * K_DIM + schunk * 8;
  char* ldsA0 = (char*)(&As[0][0]) + wave * 1024;  // + slot*16384 + issue*8192
  char* ldsB0 = (char*)(&Bs[0][0]) + wave * 1024;

  // read swizzle: phys chunk = (hi ^ ((lo>>1)&3)), in shorts:
  const int csw = (hi ^ ((lo >> 1) & 3)) * 8;
  const int aro = (wm * 128 + lo) * 32 + csw;      // + mi*512 (+2048 lower half)
  const int bro = (wn * 64 + lo) * 32 + csw;       // + ni*512

  float bz[4];
#pragma unroll
  for (int ni = 0; ni < 4; ++ni)
    bz[ni] = bias[bcol * 256 + wn * 64 + ni * 16 + lo];

  f32x4v acc[8][4] = {};

#define STAGE_A(koff, ss)                                                      \
  async_copy16(ldsA0 + (ss) * 16384, srcA + (koff));                           \
  async_copy16(ldsA0 + (ss) * 16384 + 8192, srcA + (size_t)128 * K_DIM + (koff));
#define STAGE_B(koff, ss)                                                      \
  async_copy16(ldsB0 + (ss) * 16384, srcB + (koff));                           \
  async_copy16(ldsB0 + (ss) * 16384 + 8192, srcB + (size_t)128 * K_DIM + (koff));

#define MFMA16(accrow, af, bf)                                                 \
  __builtin_amdgcn_s_setprio(1);                                               \
  _Pragma("unroll")                                                            \
  for (int mi = 0; mi < 4; ++mi)                                               \
    _Pragma("unroll")                                                          \
    for (int ni = 0; ni < 4; ++ni)                                             \
      acc[(accrow) + mi][ni] = __builtin_amdgcn_mfma_f32_16x16x32_bf16(        \
          (af)[mi], (bf)[ni], acc[(accrow) + mi][ni], 0, 0, 0);                \
  __builtin_amdgcn_s_setprio(0);

  // prologue: stage groups 0,1,2 into slots 0,1,2 (12 loads/wave);
  // vmcnt(4) -> stages 0,1 landed (slot 2 in flight)
  STAGE_A(0, 0);  STAGE_B(0, 0);
  STAGE_A(32, 1); STAGE_B(32, 1);
  STAGE_A(64, 2); STAGE_B(64, 2);
  asm volatile("s_waitcnt vmcnt(4)" ::: "memory");
  __builtin_amdgcn_s_barrier();

  int s0 = 0;   // slot of group 2p
  for (int p = 0; p < 65; ++p) {
    const int g0 = 2 * p, g1 = g0 + 1;
    const int s1  = (s0 + 1 == 5) ? 0 : s0 + 1;
    const int sw0 = (s0 + 3 >= 5) ? s0 - 2 : s0 + 3;   // (g0+3)%5
    const int sw1 = (sw0 + 1 == 5) ? 0 : sw0 + 1;      // (g1+3)%5
    const size_t ko0 = (size_t)((g0 + 3 <= NGRP - 1) ? g0 + 3 : g0 - 2) * 32;
    const size_t ko1 = (size_t)((g1 + 3 <= NGRP - 1) ? g1 + 3 : g1 - 2) * 32;
    const short* A0 = &As[0][0] + s0 * 8192;
    const short* B0 = &Bs[0][0] + s0 * 8192;
    const short* A1 = &As[0][0] + s1 * 8192;
    const short* B1 = &Bs[0][0] + s1 * 8192;

    short8 a0u[4], a0l[4], b0[4], a1u[4], a1l[4], b1[4];
    // R0: g0 upper-A + g0 B
#pragma unroll
    for (int mi = 0; mi < 4; ++mi)
      a0u[mi] = *(const short8*)(&A0[aro + mi * 512]);
#pragma unroll
    for (int ni = 0; ni < 4; ++ni)
      b0[ni] = *(const short8*)(&B0[bro + ni * 512]);
    // M0: g0 upper
    MFMA16(0, a0u, b0)
    // R1: g0 lower-A + stage A(ko0)
#pragma unroll
    for (int mi = 0; mi < 4; ++mi)
      a0l[mi] = *(const short8*)(&A0[aro + 2048 + mi * 512]);
    STAGE_A(ko0, sw0);
    // M1: g0 lower (b0 dies after)
    MFMA16(4, a0l, b0)
    // R2: g1 upper-A + g1 B + stage B(ko0)
#pragma unroll
    for (int mi = 0; mi < 4; ++mi)
      a1u[mi] = *(const short8*)(&A1[aro + mi * 512]);
#pragma unroll
    for (int ni = 0; ni < 4; ++ni)
      b1[ni] = *(const short8*)(&B1[bro + ni * 512]);
    STAGE_B(ko0, sw0);
    // M2: g1 upper
    MFMA16(0, a1u, b1)
    // R3: g1 lower-A + stage A,B(ko1)
#pragma unroll
    for (int mi = 0; mi < 4; ++mi)
      a1l[mi] = *(const short8*)(&A1[aro + 2048 + mi * 512]);
    STAGE_A(ko1, sw1);
    STAGE_B(ko1, sw1);
    // M3: g1 lower
    MFMA16(4, a1l, b1)

    asm volatile("s_waitcnt vmcnt(4)" ::: "memory");  // stage(2p+3) landed
    __builtin_amdgcn_s_barrier();
    s0 = (s0 + 2 >= 5) ? s0 - 3 : s0 + 2;
  }
  asm volatile("s_waitcnt vmcnt(0)" ::: "memory");    // drain dead stages

#pragma unroll
  for (int mi = 0; mi < 8; ++mi) {
#pragma unroll
    for (int ni = 0; ni < 4; ++ni) {
      const int r0 = brow * 256 + wm * 128 + mi * 16 + hi * 4;
      const int c0 = bcol * 256 + wn * 64 + ni * 16 + lo;
#pragma unroll
      for (int j = 0; j < 4; ++j)
        C[(size_t)(r0 + j) * N_DIM + c0] = acc[mi][ni][j] + bz[ni];
    }
  }
#undef MFMA16
#undef STAGE_A
#undef STAGE_B
}

extern "C" void kernel_launch(void* const* d_in, const int* in_sizes, int n_in,
                              void* d_out, int out_size, void* d_ws, size_t ws_size,
                              hipStream_t stream) {
  const float* x      = (const float*)d_in[0];
  const float* scores = (const float*)d_in[1];
  const float* Wb     = (const float*)d_in[2];
  const float* bb     = (const float*)d_in[3];
  const float* gW     = (const float*)d_in[4];
  const float* Wr     = (const float*)d_in[5];
  const float* lA     = (const float*)d_in[6];
  const float* lB     = (const float*)d_in[7];
  const int*   midx   = (const int*)d_in[8];
  const int*   kk     = (const int*)d_in[9];
  float* out = (float*)d_out;

  char* ws = (char*)d_ws;
  short* xa    = (short*)ws;                                        // 136,314,880 B
  short* wa    = (short*)(ws + 136314880u);                         //  34,078,720 B
  float* gated = (float*)(ws + 136314880u + 34078720u);             //     131,072 B
  short* lAb   = (short*)(ws + 136314880u + 34078720u + 131072u + 128u);  // 262,144 B

  prep_k<<<45760, 256, 0, stream>>>(x, Wb, lB, lA, gW, xa, wa, lAb, gated);
  lora_t_k<<<512, 256, 0, stream>>>(xa, lAb, gated, Wr, scores, midx, kk, xa);
  gemm_k<<<1024, 512, 0, stream>>>(xa, wa, bb, out);
}

// Round 15
// 652.693 us; speedup vs baseline: 1.0385x; 1.0385x over previous
//
#include <hip/hip_runtime.h>
#include <hip/hip_bf16.h>

// DynaLoRALinear via K-augmented bf16 GEMM:
//   x_aug[row][0:4096]=bf16(x), [4096:4128]=gate*t, [4128:4160]=0
//   W_aug[o][0:4096]=bf16(W_base), [4096+e*8+r]=bf16(lora_B[e,o,r]), rest 0
//   out = x_aug @ W_aug^T + b_base   (M=16384, N=4096, K=4160)
// FINAL (R12 config, best measured 656us):
//   prep_k   = cvt_x + cvt_w + cvt_la + gated (block-range dispatch)
//   lora_t_k = pipelined LoRA-A GEMM (ring-4, vmcnt(2)) + inline gate
//   gemm_k   = R8: 256x256 tile, 8 waves, ring-of-5 K=32 slots (160 KB LDS),
//              1 barrier + vmcnt(4) per 2-group pair (natural GROUP order —
//              R4/R13 manual fine-interleaves both regressed), 16x16x32 MFMA,
//              T2 XOR swizzle (conflicts=0), T5 setprio, T1 XCD swizzle.
//   Ladder: 705 -> 632 -> 598 -> 519 -> 488 us (gemm), 1056 -> 656 us total.

typedef short short8 __attribute__((ext_vector_type(8)));
typedef float f32x4v __attribute__((ext_vector_type(4)));

#define M_DIM 16384
#define N_DIM 4096
#define K_DIM 4160   // 65 * 64 = 130 * 32
#define D_DIM 4096
#define NGRP 130     // 32-wide K groups

__device__ __forceinline__ unsigned short f2b(float f) {
  unsigned u = __builtin_bit_cast(unsigned, f);
  return (unsigned short)((u + 0x7FFFu + ((u >> 16) & 1u)) >> 16);  // RNE
}
__device__ __forceinline__ void async_copy16(void* lds, const void* g) {
  __builtin_amdgcn_global_load_lds(
      (const __attribute__((address_space(1))) void*)g,
      (__attribute__((address_space(3))) void*)lds, 16, 0, 0);
}
// 64-col (128 B-row) LDS tiles: phys 16B-slot p of row r holds logical
// l = p ^ (r&7); read logical l at p = l ^ (r&7).
__device__ __forceinline__ short8 frag_ld(const short* base, int row, int ks, int hi, int lo) {
  return *(const short8*)(&base[row * 64 + (((ks * 4 + hi) ^ (lo & 7)) * 8)]);
}
__device__ __forceinline__ short8 cvt8(const float* src) {
  float4 a = *(const float4*)(src);
  float4 b = *(const float4*)(src + 4);
  short8 o;
  o[0] = (short)f2b(a.x); o[1] = (short)f2b(a.y);
  o[2] = (short)f2b(a.z); o[3] = (short)f2b(a.w);
  o[4] = (short)f2b(b.x); o[5] = (short)f2b(b.y);
  o[6] = (short)f2b(b.z); o[7] = (short)f2b(b.w);
  return o;
}

// ---- K1 (fused prep): blocks [0,33280)        cvt_x  -> xa
//                       blocks [33280,41600)    cvt_w  -> wa (+lora_B pack)
//                       blocks [41600,41664)    cvt_la -> lAb
//                       blocks [41664,45760)    gated[b][j] = x_pooled . gW[j]
__global__ __launch_bounds__(256) void prep_k(const float* __restrict__ x,
                                              const float* __restrict__ Wb,
                                              const float* __restrict__ lB,
                                              const float* __restrict__ lA,
                                              const float* __restrict__ gW,
                                              short* __restrict__ xa,
                                              short* __restrict__ wa,
                                              short* __restrict__ lAb,
                                              float* __restrict__ gated) {
  __shared__ float red[8][4];
  const unsigned bid = blockIdx.x;
  const int tid = threadIdx.x;
  if (bid < 33280u) {
    size_t idx = (size_t)bid * 256 + tid;   // 16384*520
    size_t row = idx / 520;
    int cc = (int)(idx % 520);
    short8 o;
    if (cc < 512) {
      o = cvt8(x + row * (size_t)D_DIM + (size_t)cc * 8);
    } else {
#pragma unroll
      for (int t = 0; t < 8; ++t) o[t] = 0;
    }
    *(short8*)(xa + row * (size_t)K_DIM + (size_t)cc * 8) = o;
  } else if (bid < 41600u) {
    size_t idx = (size_t)(bid - 33280u) * 256 + tid;   // 4096*520
    size_t row = idx / 520;
    int cc = (int)(idx % 520);
    short8 o;
    if (cc < 512) {
      o = cvt8(Wb + row * (size_t)D_DIM + (size_t)cc * 8);
    } else if (cc < 516) {
      int e = cc - 512;
      o = cvt8(lB + (size_t)e * (D_DIM * 8) + row * 8);
    } else {
#pragma unroll
      for (int t = 0; t < 8; ++t) o[t] = 0;
    }
    *(short8*)(wa + row * (size_t)K_DIM + (size_t)cc * 8) = o;
  } else if (bid < 41664u) {
    size_t i = (size_t)(bid - 41600u) * 256 + tid;  // 16384 chunks of 8
    *(short8*)(lAb + i * 8) = cvt8(lA + i * 8);
  } else {
    const int j = (int)(bid - 41664u);   // 0..4095
    float acc[8];
#pragma unroll
    for (int b = 0; b < 8; ++b) acc[b] = 0.f;
    const float* w = gW + (size_t)j * D_DIM;
    for (int i = tid * 4; i < D_DIM; i += 1024) {
      float4 wv = *(const float4*)(w + i);
#pragma unroll
      for (int b = 0; b < 8; ++b) {
        const float* p = x + ((size_t)b * 2048 + 2047) * D_DIM + i;
        float4 pv = *(const float4*)p;
        acc[b] += wv.x * pv.x + wv.y * pv.y + wv.z * pv.z + wv.w * pv.w;
      }
    }
    const int lane = tid & 63, wv_ = tid >> 6;
#pragma unroll
    for (int b = 0; b < 8; ++b) {
      float v = acc[b];
      v += __shfl_down(v, 32); v += __shfl_down(v, 16); v += __shfl_down(v, 8);
      v += __shfl_down(v, 4);  v += __shfl_down(v, 2);  v += __shfl_down(v, 1);
      if (lane == 0) red[b][wv_] = v;
    }
    __syncthreads();
    if (tid < 8)
      gated[(size_t)tid * D_DIM + j] = red[tid][0] + red[tid][1] + red[tid][2] + red[tid][3];
  }
}

// ---- K5: LoRA-A projection, pipelined. 512 blocks x 32 rows, 4 waves
// (wave w -> rows (w>>1)*16, cols (w&1)*16). LDS ring-4 of K=64 slots,
// stage d=2, vmcnt(2) + 1 barrier/iter. Epilogue recomputes this block's
// batch gate from gated/Wr/scores (removes full-device gate_k launch).
__global__ __launch_bounds__(256) void lora_t_k(const short* __restrict__ XA,
                                                const short* __restrict__ LAb,
                                                const float* __restrict__ gated,
                                                const float* __restrict__ Wr,
                                                const float* __restrict__ scores,
                                                const int* __restrict__ midx_p,
                                                const int* __restrict__ kp,
                                                short* __restrict__ xa_w) {
  __shared__ short As[4][2048];   // 4 slots x (32 rows x 64 K)
  __shared__ short Bs[4][2048];
  __shared__ float Lp[4][7];
  __shared__ float Ls[7];
  __shared__ float gateS[4];
  const int tid = threadIdx.x, lane = tid & 63, wave = tid >> 6;
  const int lo = lane & 15, hi = lane >> 4;
  const int wr = (wave >> 1) * 16;       // row tile 0/16
  const int wc = (wave & 1) * 16;        // col tile 0/16
  const size_t row0 = (size_t)blockIdx.x * 32;
  const int srow = tid >> 3;
  const int sslot = (tid & 7) ^ (srow & 7);
  const short* gA = XA + (row0 + srow) * (size_t)K_DIM + sslot * 8;
  const short* gB = LAb + (size_t)srow * D_DIM + sslot * 8;
  f32x4v acc = {};

#define LSTAGE(g)                                                              \
  async_copy16((char*)&As[(g) & 3][0] + wave * 1024, gA + (size_t)(g) * 64);   \
  async_copy16((char*)&Bs[(g) & 3][0] + wave * 1024, gB + (size_t)(g) * 64);

  LSTAGE(0)
  LSTAGE(1)
  asm volatile("s_waitcnt vmcnt(2)" ::: "memory");   // slot 0 landed
  __builtin_amdgcn_s_barrier();

  for (int g = 0; g < 64; ++g) {
    const short* Atile = &As[g & 3][0];
    const short* Btile = &Bs[g & 3][0];
    short8 a0 = frag_ld(Atile, wr + lo, 0, hi, lo);
    short8 a1 = frag_ld(Atile, wr + lo, 1, hi, lo);
    short8 b0 = frag_ld(Btile, wc + lo, 0, hi, lo);
    short8 b1 = frag_ld(Btile, wc + lo, 1, hi, lo);
    acc = __builtin_amdgcn_mfma_f32_16x16x32_bf16(a0, b0, acc, 0, 0, 0);
    acc = __builtin_amdgcn_mfma_f32_16x16x32_bf16(a1, b1, acc, 0, 0, 0);
    if (g < 62) {
      LSTAGE(g + 2)
      asm volatile("s_waitcnt vmcnt(2)" ::: "memory");  // slot g+1 landed
    } else {
      asm volatile("s_waitcnt vmcnt(0)" ::: "memory");  // tail drain
    }
    __builtin_amdgcn_s_barrier();
  }

  // ---- inline gate for this block's batch
  const int bblk = (int)(row0 >> 11);
  {
    float ac7[7];
#pragma unroll
    for (int m = 0; m < 7; ++m) ac7[m] = 0.f;
    const float* gb = gated + (size_t)bblk * D_DIM;
    for (int i = tid * 4; i < D_DIM; i += 1024) {   // 4 iterations
      float4 g4 = *(const float4*)(gb + i);
#pragma unroll
      for (int m = 0; m < 7; ++m) {
        float4 w4 = *(const float4*)(Wr + (size_t)m * D_DIM + i);
        ac7[m] += w4.x * g4.x + w4.y * g4.y + w4.z * g4.z + w4.w * g4.w;
      }
    }
#pragma unroll
    for (int m = 0; m < 7; ++m) {
      float v = ac7[m];
      v += __shfl_xor(v, 1); v += __shfl_xor(v, 2); v += __shfl_xor(v, 4);
      v += __shfl_xor(v, 8); v += __shfl_xor(v, 16); v += __shfl_xor(v, 32);
      if (lane == m) Lp[wave][m] = v;
    }
    __syncthreads();
    if (tid < 7) Ls[tid] = Lp[0][tid] + Lp[1][tid] + Lp[2][tid] + Lp[3][tid];
    __syncthreads();
    if (tid == 0) {
      float mx = -1e30f;
      for (int m = 0; m < 7; ++m) mx = fmaxf(mx, Ls[m]);
      float s = 0.f;
      for (int m = 0; m < 7; ++m) s += expf(Ls[m] - mx);
      const int mi = midx_p[0];
      const float mp = expf(Ls[mi] - mx) / s;
      int kv = kp[0]; if (kv < 1) kv = 1;
      int klo = kv >> 1; if (klo < 1) klo = 1;
      float sc[4];
#pragma unroll
      for (int e = 0; e < 4; ++e) sc[e] = scores[bblk * 4 + e];
#pragma unroll
      for (int e = 0; e < 4; ++e) {
        int rank = 0;
#pragma unroll
        for (int e2 = 0; e2 < 4; ++e2)
          rank += (sc[e2] > sc[e] || (sc[e2] == sc[e] && e2 < e)) ? 1 : 0;
        gateS[e] = (mp > 0.5f) ? ((rank < kv) ? 1.0f / (float)kv : 0.f)
                               : ((rank < klo) ? 1.0f / (float)klo : 0.f);
      }
    }
    __syncthreads();
  }

  const int col = wc + lo;
  const float gv = gateS[col >> 3];
#pragma unroll
  for (int j = 0; j < 4; ++j) {
    const size_t r = row0 + wr + hi * 4 + j;
    xa_w[r * (size_t)K_DIM + 4096 + col] = (short)f2b(acc[j] * gv);
  }
#undef LSTAGE
}

// ---- K6: main GEMM (R8 exact). Ring-of-5 K=32 slots (160 KB); barrier +
// vmcnt(4) every TWO groups; pair = one scheduling region (24 ds_read +
// 64 MFMA + 8 gloads), natural GROUP order. Stage distance d=3.
__global__ __launch_bounds__(512, 2) void gemm_k(const short* __restrict__ A,
                                                 const short* __restrict__ B,
                                                 const float* __restrict__ bias,
                                                 float* __restrict__ C) {
  __shared__ short As[5][8192];   // 5 x 16 KB (256 rows x 32 K)
  __shared__ short Bs[5][8192];
  const int tid = threadIdx.x;
  const int lane = tid & 63;
  const int wave = tid >> 6;            // 0..7
  const int wm = wave >> 2;             // 0..1 -> rows wm*128..+128
  const int wn = wave & 3;              // 0..3 -> cols wn*64..+64
  const int lo = lane & 15, hi = lane >> 4;

  // T1: XCD swizzle (1024 blocks, 8 XCDs, bijective)
  const int wg = (blockIdx.x & 7) * 128 + (blockIdx.x >> 3);
  const int brow = wg >> 4;             // 0..63
  const int bcol = wg & 15;             // 0..15

  // staging: 512 thr x 16 B covers 128 rows x 32 K; row = tid>>2, phys chunk
  // tid&3, logical = phys ^ ((row>>1)&3) = phys ^ ((tid>>3)&3)
  const int srow = tid >> 2;
  const int schunk = (tid & 3) ^ ((tid >> 3) & 3);
  const short* srcA = A + (size_t)(brow * 256 + srow) * K_DIM + schunk * 8;
  const short* srcB = B + (size_t)(bcol * 256 + srow) * K_DIM + schunk * 8;
  char* ldsA0 = (char*)(&As[0][0]) + wave * 1024;  // + slot*16384 + issue*8192
  char* ldsB0 = (char*)(&Bs[0][0]) + wave * 1024;

  // read swizzle: phys chunk = (hi ^ ((lo>>1)&3)), in shorts:
  const int csw = (hi ^ ((lo >> 1) & 3)) * 8;
  const int aro = (wm * 128 + lo) * 32 + csw;      // + mi*512 (+2048 lower half)
  const int bro = (wn * 64 + lo) * 32 + csw;       // + ni*512

  float bz[4];
#pragma unroll
  for (int ni = 0; ni < 4; ++ni)
    bz[ni] = bias[bcol * 256 + wn * 64 + ni * 16 + lo];

  f32x4v acc[8][4] = {};

#define STAGE_A(koff, ss)                                                      \
  async_copy16(ldsA0 + (ss) * 16384, srcA + (koff));                           \
  async_copy16(ldsA0 + (ss) * 16384 + 8192, srcA + (size_t)128 * K_DIM + (koff));
#define STAGE_B(koff, ss)                                                      \
  async_copy16(ldsB0 + (ss) * 16384, srcB + (koff));                           \
  async_copy16(ldsB0 + (ss) * 16384 + 8192, srcB + (size_t)128 * K_DIM + (koff));

// one group: read 12 frags from slot s, MFMA upper, stage, MFMA lower
#define GROUP(s, ko, sw)                                                       \
  {                                                                            \
    const short* Aslot = &As[0][0] + (s) * 8192;                               \
    const short* Bslot = &Bs[0][0] + (s) * 8192;                               \
    short8 afr[4], afr2[4], bfr[4];                                            \
    _Pragma("unroll")                                                          \
    for (int mi = 0; mi < 4; ++mi)                                             \
      afr[mi] = *(const short8*)(&Aslot[aro + mi * 512]);                      \
    _Pragma("unroll")                                                          \
    for (int ni = 0; ni < 4; ++ni)                                             \
      bfr[ni] = *(const short8*)(&Bslot[bro + ni * 512]);                      \
    _Pragma("unroll")                                                          \
    for (int mi = 0; mi < 4; ++mi)                                             \
      afr2[mi] = *(const short8*)(&Aslot[aro + 2048 + mi * 512]);              \
    __builtin_amdgcn_s_setprio(1);                                             \
    _Pragma("unroll")                                                          \
    for (int mi = 0; mi < 4; ++mi)                                             \
      _Pragma("unroll")                                                        \
      for (int ni = 0; ni < 4; ++ni)                                           \
        acc[mi][ni] = __builtin_amdgcn_mfma_f32_16x16x32_bf16(                 \
            afr[mi], bfr[ni], acc[mi][ni], 0, 0, 0);                           \
    __builtin_amdgcn_s_setprio(0);                                             \
    STAGE_A((ko), (sw));                                                       \
    STAGE_B((ko), (sw));                                                       \
    __builtin_amdgcn_s_setprio(1);                                             \
    _Pragma("unroll")                                                          \
    for (int mi = 0; mi < 4; ++mi)                                             \
      _Pragma("unroll")                                                        \
      for (int ni = 0; ni < 4; ++ni)                                           \
        acc[mi + 4][ni] = __builtin_amdgcn_mfma_f32_16x16x32_bf16(             \
            afr2[mi], bfr[ni], acc[mi + 4][ni], 0, 0, 0);                      \
    __builtin_amdgcn_s_setprio(0);                                             \
  }

  // prologue: stage groups 0,1,2 into slots 0,1,2 (12 loads/wave);
  // vmcnt(4) -> stages 0,1 landed (slot 2 in flight)
  STAGE_A(0, 0);  STAGE_B(0, 0);
  STAGE_A(32, 1); STAGE_B(32, 1);
  STAGE_A(64, 2); STAGE_B(64, 2);
  asm volatile("s_waitcnt vmcnt(4)" ::: "memory");
  __builtin_amdgcn_s_barrier();

  int s0 = 0;   // slot of group 2p
  for (int p = 0; p < 65; ++p) {
    const int g0 = 2 * p, g1 = g0 + 1;
    const int s1  = (s0 + 1 == 5) ? 0 : s0 + 1;
    const int sw0 = (s0 + 3 >= 5) ? s0 - 2 : s0 + 3;   // (g0+3)%5
    const int sw1 = (sw0 + 1 == 5) ? 0 : sw0 + 1;      // (g1+3)%5
    const size_t ko0 = (size_t)((g0 + 3 <= NGRP - 1) ? g0 + 3 : g0 - 2) * 32;
    const size_t ko1 = (size_t)((g1 + 3 <= NGRP - 1) ? g1 + 3 : g1 - 2) * 32;

    GROUP(s0, ko0, sw0)
    GROUP(s1, ko1, sw1)

    asm volatile("s_waitcnt vmcnt(4)" ::: "memory");  // stage(2p+3) landed
    __builtin_amdgcn_s_barrier();
    s0 = (s0 + 2 >= 5) ? s0 - 3 : s0 + 2;
  }
  asm volatile("s_waitcnt vmcnt(0)" ::: "memory");    // drain dead stages

#pragma unroll
  for (int mi = 0; mi < 8; ++mi) {
#pragma unroll
    for (int ni = 0; ni < 4; ++ni) {
      const int r0 = brow * 256 + wm * 128 + mi * 16 + hi * 4;
      const int c0 = bcol * 256 + wn * 64 + ni * 16 + lo;
#pragma unroll
      for (int j = 0; j < 4; ++j)
        C[(size_t)(r0 + j) * N_DIM + c0] = acc[mi][ni][j] + bz[ni];
    }
  }
#undef GROUP
#undef STAGE_A
#undef STAGE_B
}

extern "C" void kernel_launch(void* const* d_in, const int* in_sizes, int n_in,
                              void* d_out, int out_size, void* d_ws, size_t ws_size,
                              hipStream_t stream) {
  const float* x      = (const float*)d_in[0];
  const float* scores = (const float*)d_in[1];
  const float* Wb     = (const float*)d_in[2];
  const float* bb     = (const float*)d_in[3];
  const float* gW     = (const float*)d_in[4];
  const float* Wr     = (const float*)d_in[5];
  const float* lA     = (const float*)d_in[6];
  const float* lB     = (const float*)d_in[7];
  const int*   midx   = (const int*)d_in[8];
  const int*   kk     = (const int*)d_in[9];
  float* out = (float*)d_out;

  char* ws = (char*)d_ws;
  short* xa    = (short*)ws;                                        // 136,314,880 B
  short* wa    = (short*)(ws + 136314880u);                         //  34,078,720 B
  float* gated = (float*)(ws + 136314880u + 34078720u);             //     131,072 B
  short* lAb   = (short*)(ws + 136314880u + 34078720u + 131072u + 128u);  // 262,144 B

  prep_k<<<45760, 256, 0, stream>>>(x, Wb, lB, lA, gW, xa, wa, lAb, gated);
  lora_t_k<<<512, 256, 0, stream>>>(xa, lAb, gated, Wr, scores, midx, kk, xa);
  gemm_k<<<1024, 512, 0, stream>>>(xa, wa, bb, out);
}